// Round 3
// baseline (9330.866 us; speedup 1.0000x reference)
//
#include <hip/hip_runtime.h>
#include <hip/hip_bf16.h>

// TextDecoder: 2-layer LSTM, B=64, H=1024, V=10000, T=32 (31 computed steps).
// Round 3: ONE persistent kernel (256 blocks x 512 threads, co-resident on
// 256 CUs) with software grid barriers; split-fp16 MFMA GEMMs (x=hi+lo/2048,
// 3 MFMAs per tile-pair -> fp32-accurate). 5 barriers/step: sumarg(t-1) is
// merged with GEMM1(t) on disjoint block ranges. Round-0 fp32 multi-kernel
// path kept as fallback if ws is too small.

#define HDIM 1024
#define BDIM 64
#define VDIM 10000
#define VPAD2 10112    // 79 * 128
#define TDIM 32
#define NBLK 256
#define NTHR 512
#define GRID_THREADS (NBLK * NTHR)

typedef _Float16 f16;
typedef _Float16 f16x8 __attribute__((ext_vector_type(8)));
typedef _Float16 f16x4 __attribute__((ext_vector_type(4)));
typedef float f32x4 __attribute__((ext_vector_type(4)));

__device__ __forceinline__ float sigmoidf_(float x) {
    return 1.0f / (1.0f + expf(-x));
}

// ---------------- grid barrier (epoch-based, agent scope) ----------------
__device__ __forceinline__ void gridbar(unsigned* cnt, unsigned* epoch,
                                        unsigned e) {
    __syncthreads();
    if (threadIdx.x == 0) {
        __threadfence();   // flush my block's writes device-wide
        unsigned a = __hip_atomic_fetch_add(cnt, 1u, __ATOMIC_ACQ_REL,
                                            __HIP_MEMORY_SCOPE_AGENT);
        if (a == NBLK * (e + 1u) - 1u) {
            __hip_atomic_store(epoch, e + 1u, __ATOMIC_RELEASE,
                               __HIP_MEMORY_SCOPE_AGENT);
        } else {
            while (__hip_atomic_load(epoch, __ATOMIC_ACQUIRE,
                                     __HIP_MEMORY_SCOPE_AGENT) <= e)
                __builtin_amdgcn_s_sleep(1);
        }
    }
    __syncthreads();
}

// ---------------- split-fp16 MFMA 64x128 tile ----------------
// C[64 x 128] (+)= A[64 x K] * B[128 x K]^T over k in [kbase, kbase+KI*32).
// A,B as fp16 hi/lo pairs, row stride HDIM. 8 waves as 2(M) x 4(N).
template <int KI>
__device__ __forceinline__ void mfma_tile(
    const f16* __restrict__ Ah, const f16* __restrict__ Al,
    const f16* __restrict__ Bh, const f16* __restrict__ Bl,
    float* __restrict__ dst, int dstStride, int n0, int kbase,
    int wave, int lane)
{
    const int wr = wave >> 2, wc = wave & 3;
    const int lm = lane & 15, quad = lane >> 4;
    const int m0 = wr * 32;
    const int nw = n0 + wc * 32;

    f32x4 aH[2][2] = {};
    f32x4 aL[2][2] = {};

    const f16* pa0 = Ah + (size_t)(m0 + lm) * HDIM + kbase + quad * 8;
    const f16* pa1 = pa0 + 16 * HDIM;
    const f16* qa0 = Al + (size_t)(m0 + lm) * HDIM + kbase + quad * 8;
    const f16* qa1 = qa0 + 16 * HDIM;
    const f16* pb0 = Bh + (size_t)(nw + lm) * HDIM + kbase + quad * 8;
    const f16* pb1 = pb0 + 16 * HDIM;
    const f16* qb0 = Bl + (size_t)(nw + lm) * HDIM + kbase + quad * 8;
    const f16* qb1 = qb0 + 16 * HDIM;

    #pragma unroll 4
    for (int kk = 0; kk < KI; kk++) {
        const int ko = kk * 32;
        f16x8 ah0 = *(const f16x8*)(pa0 + ko);
        f16x8 ah1 = *(const f16x8*)(pa1 + ko);
        f16x8 al0 = *(const f16x8*)(qa0 + ko);
        f16x8 al1 = *(const f16x8*)(qa1 + ko);
        f16x8 bh0 = *(const f16x8*)(pb0 + ko);
        f16x8 bh1 = *(const f16x8*)(pb1 + ko);
        f16x8 bl0 = *(const f16x8*)(qb0 + ko);
        f16x8 bl1 = *(const f16x8*)(qb1 + ko);

        aH[0][0] = __builtin_amdgcn_mfma_f32_16x16x32_f16(ah0, bh0, aH[0][0], 0, 0, 0);
        aH[0][1] = __builtin_amdgcn_mfma_f32_16x16x32_f16(ah0, bh1, aH[0][1], 0, 0, 0);
        aH[1][0] = __builtin_amdgcn_mfma_f32_16x16x32_f16(ah1, bh0, aH[1][0], 0, 0, 0);
        aH[1][1] = __builtin_amdgcn_mfma_f32_16x16x32_f16(ah1, bh1, aH[1][1], 0, 0, 0);

        aL[0][0] = __builtin_amdgcn_mfma_f32_16x16x32_f16(ah0, bl0, aL[0][0], 0, 0, 0);
        aL[0][1] = __builtin_amdgcn_mfma_f32_16x16x32_f16(ah0, bl1, aL[0][1], 0, 0, 0);
        aL[1][0] = __builtin_amdgcn_mfma_f32_16x16x32_f16(ah1, bl0, aL[1][0], 0, 0, 0);
        aL[1][1] = __builtin_amdgcn_mfma_f32_16x16x32_f16(ah1, bl1, aL[1][1], 0, 0, 0);

        aL[0][0] = __builtin_amdgcn_mfma_f32_16x16x32_f16(al0, bh0, aL[0][0], 0, 0, 0);
        aL[0][1] = __builtin_amdgcn_mfma_f32_16x16x32_f16(al0, bh1, aL[0][1], 0, 0, 0);
        aL[1][0] = __builtin_amdgcn_mfma_f32_16x16x32_f16(al1, bh0, aL[1][0], 0, 0, 0);
        aL[1][1] = __builtin_amdgcn_mfma_f32_16x16x32_f16(al1, bh1, aL[1][1], 0, 0, 0);
    }

    #pragma unroll
    for (int rt = 0; rt < 2; rt++)
        #pragma unroll
        for (int ct = 0; ct < 2; ct++)
            #pragma unroll
            for (int r = 0; r < 4; r++) {
                int row = m0 + rt * 16 + quad * 4 + r;
                int col = nw + ct * 16 + lm;
                dst[(size_t)row * dstStride + col] =
                    aH[rt][ct][r] + aL[rt][ct][r] * (1.0f / 2048.0f);
            }
}

// fp32 -> fp16 hi/lo split, float4-vectorized grid-stride
__device__ __forceinline__ void conv4(const float* __restrict__ src,
                                      f16* __restrict__ hi, f16* __restrict__ lo,
                                      int n, int gid) {
    for (int i = gid * 4; i < n; i += GRID_THREADS * 4) {
        float4 x = *(const float4*)(src + i);
        f16x4 h, l;
        h.x = (f16)x.x; l.x = (f16)((x.x - (float)h.x) * 2048.0f);
        h.y = (f16)x.y; l.y = (f16)((x.y - (float)h.y) * 2048.0f);
        h.z = (f16)x.z; l.z = (f16)((x.z - (float)h.z) * 2048.0f);
        h.w = (f16)x.w; l.w = (f16)((x.w - (float)h.w) * 2048.0f);
        *(f16x4*)(hi + i) = h;
        *(f16x4*)(lo + i) = l;
    }
}

__device__ __forceinline__ void conv4pad(const float* __restrict__ src,
                                         f16* __restrict__ hi, f16* __restrict__ lo,
                                         int n_src, int n_pad, int gid) {
    for (int i = gid * 4; i < n_pad; i += GRID_THREADS * 4) {
        float4 x = (i < n_src) ? *(const float4*)(src + i)
                               : make_float4(0.f, 0.f, 0.f, 0.f);
        f16x4 h, l;
        h.x = (f16)x.x; l.x = (f16)((x.x - (float)h.x) * 2048.0f);
        h.y = (f16)x.y; l.y = (f16)((x.y - (float)h.y) * 2048.0f);
        h.z = (f16)x.z; l.z = (f16)((x.z - (float)h.z) * 2048.0f);
        h.w = (f16)x.w; l.w = (f16)((x.w - (float)h.w) * 2048.0f);
        *(f16x4*)(hi + i) = h;
        *(f16x4*)(lo + i) = l;
    }
}

// ---------------- the persistent kernel ----------------
__global__ __launch_bounds__(NTHR, 2) void decoder_persist(
    const float* __restrict__ hidden, const float* __restrict__ cellin,
    const int* __restrict__ captions, const int* __restrict__ tfmask,
    const float* __restrict__ Wih0, const float* __restrict__ bih0,
    const float* __restrict__ bhh0, const float* __restrict__ bih1,
    const float* __restrict__ bhh1, const float* __restrict__ bout,
    const float* __restrict__ Whh0, const float* __restrict__ Wih1,
    const float* __restrict__ Whh1, const float* __restrict__ Wout,
    float* __restrict__ out, char* __restrict__ wsb)
{
    const int blk = blockIdx.x;
    const int tid = threadIdx.x;
    const int wave = tid >> 6, lane = tid & 63;
    const int gid = blk * NTHR + tid;

    unsigned* cnt   = (unsigned*)(wsb);
    unsigned* epoch = (unsigned*)(wsb + 128);
    int*   amax = (int*)(wsb + 256);
    float* c1   = (float*)(wsb + 512);
    float* c2   = (float*)(wsb + 262656);
    f16* h1h = (f16*)(wsb + 524800);
    f16* h1l = (f16*)(wsb + 655872);
    f16* h2h = (f16*)(wsb + 786944);
    f16* h2l = (f16*)(wsb + 918016);
    float* partA = (float*)(wsb + 1049088);    // 6 slabs x 64x4096
    float* partB = (float*)(wsb + 7340544);    // 8 slabs x 64x4096
    float* partC = (float*)(wsb + 15729152);   // 3 slabs x 64xVPAD2
    f16* Whh0h = (f16*)(wsb + 23495168);
    f16* Whh0l = (f16*)(wsb + 31883776);
    f16* Wih1h = (f16*)(wsb + 40272384);
    f16* Wih1l = (f16*)(wsb + 48660992);
    f16* Whh1h = (f16*)(wsb + 57049600);
    f16* Whh1l = (f16*)(wsb + 65438208);
    f16* Wouth = (f16*)(wsb + 73826816);
    f16* Woutl = (f16*)(wsb + 94536192);

    __shared__ unsigned long long red[8];

    unsigned e = 0;

    // ---- Phase 0: init states + convert weights ----
    if (gid < BDIM * HDIM) {
        float a = hidden[gid];
        float b = hidden[BDIM * HDIM + gid];
        c1[gid] = cellin[gid];
        c2[gid] = cellin[BDIM * HDIM + gid];
        f16 ah = (f16)a; h1h[gid] = ah; h1l[gid] = (f16)((a - (float)ah) * 2048.0f);
        f16 bh = (f16)b; h2h[gid] = bh; h2l[gid] = (f16)((b - (float)bh) * 2048.0f);
    }
    for (int i = gid; i < BDIM * VDIM; i += GRID_THREADS) {
        int b = i / VDIM, v = i - b * VDIM;
        out[(size_t)b * TDIM * VDIM + v] = (v == captions[b * TDIM]) ? 1.0f : 0.0f;
    }
    conv4(Whh0, Whh0h, Whh0l, HDIM * 4 * HDIM, gid);
    conv4(Wih1, Wih1h, Wih1l, HDIM * 4 * HDIM, gid);
    conv4(Whh1, Whh1h, Whh1l, HDIM * 4 * HDIM, gid);
    conv4pad(Wout, Wouth, Woutl, VDIM * HDIM, VPAD2 * HDIM, gid);
    gridbar(cnt, epoch, e); e++;

    for (int t = 1; t < TDIM; t++) {
        // ---- P1: blocks 0..63 -> sumarg(t-1); blocks 64..255 -> GEMM1(t) ----
        if (blk < 64) {
            if (t > 1) {
                const int b = blk;
                const int trow = t - 1;
                const float* p0 = partC + (size_t)b * VPAD2;
                const float* p1 = partC + (size_t)64 * VPAD2 + (size_t)b * VPAD2;
                const float* p2 = partC + (size_t)128 * VPAD2 + (size_t)b * VPAD2;
                float* orow = out + (size_t)b * TDIM * VDIM + (size_t)trow * VDIM;
                unsigned long long best = 0ull;
                for (int v = tid; v < VDIM; v += NTHR) {
                    float s = p0[v] + p1[v] + p2[v] + bout[v];
                    orow[v] = s;
                    unsigned u = __float_as_uint(s);
                    u = (u & 0x80000000u) ? ~u : (u | 0x80000000u);
                    unsigned long long en = ((unsigned long long)u << 32) | (unsigned)(~v);
                    if (en > best) best = en;
                }
                #pragma unroll
                for (int off = 32; off > 0; off >>= 1) {
                    unsigned long long o = __shfl_down(best, off, 64);
                    if (o > best) best = o;
                }
                if (lane == 0) red[wave] = best;
                __syncthreads();
                if (tid == 0) {
                    #pragma unroll
                    for (int w = 1; w < 8; w++)
                        if (red[w] > best) best = red[w];
                    amax[b] = (int)(~(unsigned)(best & 0xffffffffull));
                }
            }
        } else {
            int idx = blk - 64;            // 0..191
            int ntile = idx & 31;
            int q = idx >> 5;              // 0..5, non-uniform klen {192,192,160,160,160,160}
            int kbase = (q < 2) ? q * 192 : 384 + (q - 2) * 160;
            float* dst = partA + (size_t)q * 64 * 4096;
            if (q < 2)
                mfma_tile<6>(h1h, h1l, Whh0h, Whh0l, dst, 4096, ntile * 128, kbase, wave, lane);
            else
                mfma_tile<5>(h1h, h1l, Whh0h, Whh0l, dst, 4096, ntile * 128, kbase, wave, lane);
        }
        gridbar(cnt, epoch, e); e++;

        // ---- P2: cell0 ----
        if (gid < BDIM * HDIM) {
            int b = gid >> 10, i = gid & 1023;
            int tok = (t == 1) ? captions[b * TDIM]
                    : (tfmask[t - 1] ? captions[b * TDIM + (t - 1)] : amax[b]);
            float g[4];
            #pragma unroll
            for (int gi = 0; gi < 4; gi++) {
                int j = gi * HDIM + i;
                float s = bih0[j] + bhh0[j] + Wih0[(size_t)j * VDIM + tok];
                #pragma unroll
                for (int q = 0; q < 6; q++) s += partA[(size_t)q * 262144 + b * 4096 + j];
                g[gi] = s;
            }
            float ig = sigmoidf_(g[0]), fg = sigmoidf_(g[1]);
            float gg = tanhf(g[2]),     og = sigmoidf_(g[3]);
            float cn = fg * c1[gid] + ig * gg;
            float hn = og * tanhf(cn);
            c1[gid] = cn;
            f16 hh = (f16)hn;
            h1h[gid] = hh; h1l[gid] = (f16)((hn - (float)hh) * 2048.0f);
        }
        gridbar(cnt, epoch, e); e++;

        // ---- P3: GEMM2 (z=0: h1@Wih1^T, z=1: h2@Whh1^T), K-split 4 ----
        {
            int z = blk >> 7, idx = blk & 127;
            int ntile = idx & 31, q = idx >> 5;
            const f16* Ah = z ? h2h : h1h;
            const f16* Al = z ? h2l : h1l;
            const f16* Bh = z ? Whh1h : Wih1h;
            const f16* Bl = z ? Whh1l : Wih1l;
            float* dst = partB + (size_t)(z * 4 + q) * 262144;
            mfma_tile<8>(Ah, Al, Bh, Bl, dst, 4096, ntile * 128, q * 256, wave, lane);
        }
        gridbar(cnt, epoch, e); e++;

        // ---- P4: cell1 ----
        if (gid < BDIM * HDIM) {
            int b = gid >> 10, i = gid & 1023;
            float g[4];
            #pragma unroll
            for (int gi = 0; gi < 4; gi++) {
                int j = gi * HDIM + i;
                float s = bih1[j] + bhh1[j];
                #pragma unroll
                for (int q = 0; q < 8; q++) s += partB[(size_t)q * 262144 + b * 4096 + j];
                g[gi] = s;
            }
            float ig = sigmoidf_(g[0]), fg = sigmoidf_(g[1]);
            float gg = tanhf(g[2]),     og = sigmoidf_(g[3]);
            float cn = fg * c2[gid] + ig * gg;
            float hn = og * tanhf(cn);
            c2[gid] = cn;
            f16 hh = (f16)hn;
            h2h[gid] = hh; h2l[gid] = (f16)((hn - (float)hh) * 2048.0f);
        }
        gridbar(cnt, epoch, e); e++;

        // ---- P5: GEMM3 logits partials, 79 tiles x K-split {352,352,320} ----
        if (blk < 237) {
            int q = blk / 79;
            int ntile = blk - q * 79;
            int kbase = q * 352;
            float* dst = partC + (size_t)q * 64 * VPAD2;
            if (q < 2)
                mfma_tile<11>(h2h, h2l, Wouth, Woutl, dst, VPAD2, ntile * 128, kbase, wave, lane);
            else
                mfma_tile<10>(h2h, h2l, Wouth, Woutl, dst, VPAD2, ntile * 128, kbase, wave, lane);
        }
        gridbar(cnt, epoch, e); e++;
    }

    // ---- final sumarg for t=31 (no amax consumer; just write out row 31) ----
    if (blk < 64) {
        const int b = blk;
        const float* p0 = partC + (size_t)b * VPAD2;
        const float* p1 = partC + (size_t)64 * VPAD2 + (size_t)b * VPAD2;
        const float* p2 = partC + (size_t)128 * VPAD2 + (size_t)b * VPAD2;
        float* orow = out + (size_t)b * TDIM * VDIM + (size_t)(TDIM - 1) * VDIM;
        for (int v = tid; v < VDIM; v += NTHR)
            orow[v] = p0[v] + p1[v] + p2[v] + bout[v];
    }
}

// =================== fp32 fallback (round-0 path) ===================
__global__ __launch_bounds__(256) void gemm_ksplit(
    const float* __restrict__ A0, const float* __restrict__ W0,
    const float* __restrict__ A1, const float* __restrict__ W1,
    float* __restrict__ part, int N, int KS)
{
    const int tid = threadIdx.x;
    const int nblk = blockIdx.x;
    const int q = blockIdx.y;
    const int z = blockIdx.z;
    const float* __restrict__ A = z ? A1 : A0;
    const float* __restrict__ W = z ? W1 : W0;
    const int klen = HDIM / KS;
    const int kbase = q * klen;
    const int n0 = nblk * 64;
    const int slab = z * KS + q;

    __shared__ float As[32][64];
    __shared__ float Ws[32][64];

    float acc[4][4] = {};
    const int ty = tid >> 4, tx = tid & 15;
    const int b0 = ty * 4, c0 = tx * 4;
    const int ldr = tid >> 2;
    const int lk  = (tid & 3) * 8;

    for (int kc = 0; kc < klen; kc += 32) {
        {
            const float* src = A + ldr * HDIM + kbase + kc + lk;
            float4 v0 = *(const float4*)(src);
            float4 v1 = *(const float4*)(src + 4);
            As[lk+0][ldr] = v0.x; As[lk+1][ldr] = v0.y;
            As[lk+2][ldr] = v0.z; As[lk+3][ldr] = v0.w;
            As[lk+4][ldr] = v1.x; As[lk+5][ldr] = v1.y;
            As[lk+6][ldr] = v1.z; As[lk+7][ldr] = v1.w;
        }
        {
            int n = n0 + ldr;
            if (n < N) {
                const float* src = W + (size_t)n * HDIM + kbase + kc + lk;
                float4 v0 = *(const float4*)(src);
                float4 v1 = *(const float4*)(src + 4);
                Ws[lk+0][ldr] = v0.x; Ws[lk+1][ldr] = v0.y;
                Ws[lk+2][ldr] = v0.z; Ws[lk+3][ldr] = v0.w;
                Ws[lk+4][ldr] = v1.x; Ws[lk+5][ldr] = v1.y;
                Ws[lk+6][ldr] = v1.z; Ws[lk+7][ldr] = v1.w;
            } else {
                #pragma unroll
                for (int i = 0; i < 8; i++) Ws[lk+i][ldr] = 0.0f;
            }
        }
        __syncthreads();
        #pragma unroll
        for (int kk = 0; kk < 32; kk++) {
            float4 a = *(const float4*)&As[kk][b0];
            float4 w = *(const float4*)&Ws[kk][c0];
            acc[0][0] += a.x*w.x; acc[0][1] += a.x*w.y; acc[0][2] += a.x*w.z; acc[0][3] += a.x*w.w;
            acc[1][0] += a.y*w.x; acc[1][1] += a.y*w.y; acc[1][2] += a.y*w.z; acc[1][3] += a.y*w.w;
            acc[2][0] += a.z*w.x; acc[2][1] += a.z*w.y; acc[2][2] += a.z*w.z; acc[2][3] += a.z*w.w;
            acc[3][0] += a.w*w.x; acc[3][1] += a.w*w.y; acc[3][2] += a.w*w.z; acc[3][3] += a.w*w.w;
        }
        __syncthreads();
    }

    float* dst = part + (size_t)slab * 64 * N;
    if (n0 + 64 <= N) {
        #pragma unroll
        for (int i = 0; i < 4; i++) {
            float4 v = make_float4(acc[i][0], acc[i][1], acc[i][2], acc[i][3]);
            *(float4*)&dst[(size_t)(b0 + i) * N + n0 + c0] = v;
        }
    } else {
        for (int i = 0; i < 4; i++)
            for (int j = 0; j < 4; j++) {
                int col = n0 + c0 + j;
                if (col < N) dst[(size_t)(b0 + i) * N + col] = acc[i][j];
            }
    }
}

__global__ __launch_bounds__(256) void cell0_fb(
    const float* __restrict__ part,
    const float* __restrict__ Wih0, const float* __restrict__ bih,
    const float* __restrict__ bhh,
    const int* __restrict__ captions, const int* __restrict__ tfmask,
    const int* __restrict__ amax,
    float* __restrict__ h1, float* __restrict__ c1, int t)
{
    int idx = blockIdx.x * 256 + threadIdx.x;
    int b = idx >> 10, i = idx & 1023;
    int tok;
    if (t == 1) tok = captions[b * TDIM];
    else tok = tfmask[t - 1] ? captions[b * TDIM + (t - 1)] : amax[b];
    float g[4];
    #pragma unroll
    for (int gi = 0; gi < 4; gi++) {
        int j = gi * HDIM + i;
        float s = bih[j] + bhh[j] + Wih0[(size_t)j * VDIM + tok];
        #pragma unroll
        for (int q = 0; q < 4; q++) s += part[(size_t)q * 262144 + b * 4096 + j];
        g[gi] = s;
    }
    float ig = sigmoidf_(g[0]), fg = sigmoidf_(g[1]);
    float gg = tanhf(g[2]),     og = sigmoidf_(g[3]);
    float cn = fg * c1[idx] + ig * gg;
    float hn = og * tanhf(cn);
    c1[idx] = cn; h1[idx] = hn;
}

__global__ __launch_bounds__(256) void cell1_fb(
    const float* __restrict__ part,
    const float* __restrict__ bih, const float* __restrict__ bhh,
    float* __restrict__ h2, float* __restrict__ c2)
{
    int idx = blockIdx.x * 256 + threadIdx.x;
    int b = idx >> 10, i = idx & 1023;
    float g[4];
    #pragma unroll
    for (int gi = 0; gi < 4; gi++) {
        int j = gi * HDIM + i;
        float s = bih[j] + bhh[j];
        #pragma unroll
        for (int q = 0; q < 8; q++) s += part[(size_t)q * 262144 + b * 4096 + j];
        g[gi] = s;
    }
    float ig = sigmoidf_(g[0]), fg = sigmoidf_(g[1]);
    float gg = tanhf(g[2]),     og = sigmoidf_(g[3]);
    float cn = fg * c2[idx] + ig * gg;
    float hn = og * tanhf(cn);
    c2[idx] = cn; h2[idx] = hn;
}

__global__ __launch_bounds__(256) void sumarg_fb(
    const float* __restrict__ part, const float* __restrict__ b_out,
    float* __restrict__ out, int* __restrict__ amax, int t)
{
    int b = blockIdx.x;
    int tid = threadIdx.x;
    const float* p0 = part + (size_t)b * VDIM;
    const float* p1 = part + (size_t)64 * VDIM + (size_t)b * VDIM;
    float* orow = out + (size_t)b * TDIM * VDIM + (size_t)t * VDIM;
    unsigned long long best = 0ull;
    for (int v = tid; v < VDIM; v += 256) {
        float s = p0[v] + p1[v] + b_out[v];
        orow[v] = s;
        unsigned u = __float_as_uint(s);
        u = (u & 0x80000000u) ? ~u : (u | 0x80000000u);
        unsigned long long e = ((unsigned long long)u << 32) | (unsigned)(~v);
        if (e > best) best = e;
    }
    #pragma unroll
    for (int off = 32; off > 0; off >>= 1) {
        unsigned long long o = __shfl_down(best, off, 64);
        if (o > best) best = o;
    }
    __shared__ unsigned long long red[4];
    if ((tid & 63) == 0) red[tid >> 6] = best;
    __syncthreads();
    if (tid == 0) {
        best = red[0];
        if (red[1] > best) best = red[1];
        if (red[2] > best) best = red[2];
        if (red[3] > best) best = red[3];
        amax[b] = (int)(~(unsigned)(best & 0xffffffffull));
    }
}

__global__ __launch_bounds__(256) void init_fb(
    const float* __restrict__ hidden, const float* __restrict__ cell,
    const int* __restrict__ captions,
    float* __restrict__ h1, float* __restrict__ c1,
    float* __restrict__ h2, float* __restrict__ c2,
    float* __restrict__ out)
{
    int idx = blockIdx.x * 256 + threadIdx.x;
    if (idx < BDIM * HDIM) {
        h1[idx] = hidden[idx];
        h2[idx] = hidden[BDIM * HDIM + idx];
        c1[idx] = cell[idx];
        c2[idx] = cell[BDIM * HDIM + idx];
    }
    if (idx < BDIM * VDIM) {
        int b = idx / VDIM, v = idx % VDIM;
        out[(size_t)b * TDIM * VDIM + v] = (v == captions[b * TDIM]) ? 1.0f : 0.0f;
    }
}

extern "C" void kernel_launch(void* const* d_in, const int* in_sizes, int n_in,
                              void* d_out, int out_size, void* d_ws, size_t ws_size,
                              hipStream_t stream)
{
    const float* hidden = (const float*)d_in[0];
    const float* cellin = (const float*)d_in[1];
    const int*   captions = (const int*)d_in[2];
    const int*   tfmask = (const int*)d_in[3];
    const float* Wih0 = (const float*)d_in[4];
    const float* Whh0 = (const float*)d_in[5];
    const float* bih0 = (const float*)d_in[6];
    const float* bhh0 = (const float*)d_in[7];
    const float* Wih1 = (const float*)d_in[8];
    const float* Whh1 = (const float*)d_in[9];
    const float* bih1 = (const float*)d_in[10];
    const float* bhh1 = (const float*)d_in[11];
    const float* Wout = (const float*)d_in[12];
    const float* bout = (const float*)d_in[13];
    float* out = (float*)d_out;

    const size_t ws_needed = 94536192ull + 20709376ull;   // ~115 MB

    if (ws_size >= ws_needed) {
        // zero the barrier state (cnt + epoch)
        hipMemsetAsync(d_ws, 0, 256, stream);
        decoder_persist<<<NBLK, NTHR, 0, stream>>>(
            hidden, cellin, captions, tfmask, Wih0, bih0, bhh0,
            bih1, bhh1, bout, Whh0, Wih1, Whh1, Wout, out, (char*)d_ws);
    } else {
        // fp32 fallback (round-0 structure)
        float* ws = (float*)d_ws;
        float* h1 = ws;
        float* c1 = ws + 65536;
        float* h2 = ws + 131072;
        float* c2 = ws + 196608;
        float* part = ws + 262144;
        int*   amax = (int*)(ws + 262144 + 8 * 262144);

        init_fb<<<2500, 256, 0, stream>>>(hidden, cellin, captions, h1, c1, h2, c2, out);
        for (int t = 1; t < TDIM; t++) {
            gemm_ksplit<<<dim3(64, 4, 1), 256, 0, stream>>>(h1, Whh0, h1, Whh0, part, 4096, 4);
            cell0_fb<<<256, 256, 0, stream>>>(part, Wih0, bih0, bhh0, captions, tfmask,
                                              amax, h1, c1, t);
            gemm_ksplit<<<dim3(64, 4, 2), 256, 0, stream>>>(h1, Wih1, h2, Whh1, part, 4096, 4);
            cell1_fb<<<256, 256, 0, stream>>>(part, bih1, bhh1, h2, c2);
            gemm_ksplit<<<dim3(157, 2, 1), 256, 0, stream>>>(h2, Wout, h2, Wout, part, 10000, 2);
            sumarg_fb<<<64, 256, 0, stream>>>(part, bout, out, amax, t);
        }
    }
}